// Round 4
// baseline (4904.794 us; speedup 1.0000x reference)
//
#include <hip/hip_runtime.h>
#include <hip/hip_bf16.h>

#define N_NODES 20000
#define N_EDGES 320000
#define N_ADJ   4
#define D       256
#define DH      128              // packed bf16x2 dwords per feature row
#define NCHUNK  4                // col chunks of 5000 rows (2.56 MB bf16 table)
#define CROWS   5000
#define RPA     80004            // row_ptr stride per adjacency (4*20000 + pad, 16B-aligned)
#define NBLK    1792             // stage grid: 7 blocks/CU * 256 CUs (co-resident)

typedef __attribute__((ext_vector_type(8))) short bf8;   // 8 bf16 (4 VGPRs)
typedef __attribute__((ext_vector_type(4))) float f4;    // MFMA accumulator

// ---------------------------------------------------------------------------
// bf16 pack/unpack helpers (RNE rounding; values are finite)
// ---------------------------------------------------------------------------

__device__ __forceinline__ unsigned f2bf_bits(float x) {
    unsigned u = __float_as_uint(x);
    return (u + 0x7FFFu + ((u >> 16) & 1u)) >> 16;
}
__device__ __forceinline__ unsigned pack_bf2(float lo, float hi) {
    return f2bf_bits(lo) | (f2bf_bits(hi) << 16);
}
__device__ __forceinline__ float bf_lo(unsigned p) { return __uint_as_float(p << 16); }
__device__ __forceinline__ float bf_hi(unsigned p) { return __uint_as_float(p & 0xFFFF0000u); }

// ---------------------------------------------------------------------------
// Soft grid barrier: perf-only chunk alignment.  Cumulative arrival counter,
// device-scope atomics, bounded spin (timeout ~34us) so correctness NEVER
// depends on grid co-residency.  Real inter-stage syncs = kernel boundaries.
// ---------------------------------------------------------------------------

__device__ __forceinline__ void soft_sync(int* bar, int gen) {
    __syncthreads();
    if (threadIdx.x == 0) {
        __hip_atomic_fetch_add(bar, 1, __ATOMIC_ACQ_REL, __HIP_MEMORY_SCOPE_AGENT);
        int target = NBLK * gen;
        int it = 0;
        while (__hip_atomic_load(bar, __ATOMIC_ACQUIRE, __HIP_MEMORY_SCOPE_AGENT) < target) {
            if (++it > 1024) break;
            __builtin_amdgcn_s_sleep(1);
        }
    }
    __syncthreads();
}

// ---------------------------------------------------------------------------
// CSR build over 4 adj x 4 col-chunks: histogram -> scan -> scatter.
// cnt/work layout: [a][chunk*20000 + r]; row_ptr: [a][i] with i=c*20000+r.
// Edge record: 32 bits = (bf16(val) << 16) | col   (col < 32768).
// ---------------------------------------------------------------------------

__global__ __launch_bounds__(256) void hist_kernel(const int* __restrict__ rows,
                                                   const int* __restrict__ cols,
                                                   int* __restrict__ cnt) {
    int e = blockIdx.x * 256 + threadIdx.x;
    int a = blockIdx.y;
    if (e < N_EDGES) {
        int r = rows[a * N_EDGES + e];
        int c = cols[a * N_EDGES + e] / CROWS;
        atomicAdd(&cnt[a * 80000 + c * N_NODES + r], 1);
    }
}

// 4 blocks x 1024 thr; 4 ints/thread via int4; shuffle wave scans.
__global__ __launch_bounds__(1024) void scan_kernel(const int4* __restrict__ cnt4,
                                                    int* __restrict__ row_ptr,
                                                    int* __restrict__ work) {
    int a = blockIdx.x, t = threadIdx.x;
    int lane = t & 63, w = t >> 6;            // 16 waves
    __shared__ int wsum[16];
    const int4* src = cnt4 + (size_t)a * 20000;      // 80000 ints = 20000 int4
    int4* rp4 = (int4*)(row_ptr + (size_t)a * RPA);
    int4* wk4 = (int4*)(work + (size_t)a * 80000);
    int carry = 0;
    for (int base = 0; base < 20000; base += 1024) {
        int i = base + t;
        int4 v = (i < 20000) ? src[i] : make_int4(0, 0, 0, 0);
        int tsum = v.x + v.y + v.z + v.w;
        int s = tsum;                          // inclusive wave scan of thread sums
        #pragma unroll
        for (int off = 1; off < 64; off <<= 1) {
            int u = __shfl_up(s, off, 64);
            if (lane >= off) s += u;
        }
        if (lane == 63) wsum[w] = s;
        __syncthreads();
        int woff = 0, total = 0;
        #pragma unroll
        for (int j = 0; j < 16; ++j) {
            int ws = wsum[j];
            woff  += (j < w) ? ws : 0;
            total += ws;
        }
        __syncthreads();
        if (i < 20000) {
            int excl = carry + woff + s - tsum;
            int4 o;
            o.x = excl; o.y = excl + v.x; o.z = o.y + v.y; o.w = o.z + v.z;
            rp4[i] = o;
            wk4[i] = o;
        }
        carry += total;
    }
    if (t == 0) row_ptr[(size_t)a * RPA + 80000] = carry;
}

__global__ __launch_bounds__(256) void scatter_kernel(const int* __restrict__ rows,
                                                      const int* __restrict__ cols,
                                                      const float* __restrict__ vals,
                                                      int* __restrict__ work,
                                                      unsigned* __restrict__ csr) {
    int e = blockIdx.x * 256 + threadIdx.x;
    int a = blockIdx.y;
    if (e < N_EDGES) {
        int r   = rows[a * N_EDGES + e];
        int col = cols[a * N_EDGES + e];
        int c   = col / CROWS;
        int idx = atomicAdd(&work[a * 80000 + c * N_NODES + r], 1);
        csr[(size_t)a * N_EDGES + idx] = (f2bf_bits(vals[a * N_EDGES + e]) << 16) | (unsigned)col;
    }
}

// ---------------------------------------------------------------------------
// W -> fragment-ordered bf16 hi/lo tables (one uint4 per lane per (ks,n) tile).
// B frag layout (16x16x32): n_idx = lane&15, k = ks*32 + (lane>>4)*8 + j.
// ---------------------------------------------------------------------------

__global__ __launch_bounds__(256) void wfrag_kernel(const float* __restrict__ W,
                                                    uint4* __restrict__ wh,
                                                    uint4* __restrict__ wl) {
    int g = blockIdx.x * 256 + threadIdx.x;   // 0..8191 = (ks*16+n)*64 + lane
    int lane = g & 63;
    int tile = g >> 6;                        // ks*16 + n
    int ks = tile >> 4, n = tile & 15;
    int m = lane & 15, quad = lane >> 4;
    int col = n * 16 + m;
    int k0  = ks * 32 + quad * 8;
    unsigned hbits[8], lbits[8];
    #pragma unroll
    for (int j = 0; j < 8; ++j) {
        float v = W[(k0 + j) * D + col];
        unsigned hb = f2bf_bits(v);
        float lo = v - __uint_as_float(hb << 16);
        hbits[j] = hb;
        lbits[j] = f2bf_bits(lo);
    }
    uint4 hh, ll;
    hh.x = hbits[0] | (hbits[1] << 16); hh.y = hbits[2] | (hbits[3] << 16);
    hh.z = hbits[4] | (hbits[5] << 16); hh.w = hbits[6] | (hbits[7] << 16);
    ll.x = lbits[0] | (lbits[1] << 16); ll.y = lbits[2] | (lbits[3] << 16);
    ll.z = lbits[4] | (lbits[5] << 16); ll.w = lbits[6] | (lbits[7] << 16);
    wh[g] = hh;
    wl[g] = ll;
}

// ---------------------------------------------------------------------------
// h = x @ W + b via bf16 MFMA hi/lo compensation.  Block = 4 waves = 4 row
// tiles; B frags staged through double-buffered LDS shared by all 4 waves.
// ---------------------------------------------------------------------------

__global__ __launch_bounds__(256) void mfma_matmul_kernel(const float* __restrict__ x,
                                                          const uint4* __restrict__ wh,
                                                          const uint4* __restrict__ wl,
                                                          const float* __restrict__ b,
                                                          unsigned* __restrict__ hp) {
    __shared__ uint4 lbuf[2][1024];           // [buf][ks*128 + hl*64 + lane], 32 KB
    int t = threadIdx.x, wid = t >> 6, lane = t & 63;
    int r0 = (blockIdx.x * 4 + wid) * 16;
    bool active = r0 < N_NODES;
    int m = lane & 15, quad = lane >> 4;

    bf8 ah[8], al[8];
    if (active) {
        const float* xr = x + (size_t)(r0 + m) * D + quad * 8;
        #pragma unroll
        for (int ks = 0; ks < 8; ++ks) {
            float4 v0 = *(const float4*)(xr + ks * 32);
            float4 v1 = *(const float4*)(xr + ks * 32 + 4);
            float xs[8] = {v0.x, v0.y, v0.z, v0.w, v1.x, v1.y, v1.z, v1.w};
            #pragma unroll
            for (int j = 0; j < 8; ++j) {
                unsigned hb = f2bf_bits(xs[j]);
                float lo = xs[j] - __uint_as_float(hb << 16);
                ah[ks][j] = (short)hb;
                al[ks][j] = (short)f2bf_bits(lo);
            }
        }
    }

    // prologue: stage n=0 fragments
    #pragma unroll
    for (int j = 0; j < 4; ++j) {
        int idx = j * 256 + t;
        int ks = idx >> 7, hl = (idx >> 6) & 1, ln = idx & 63;
        lbuf[0][idx] = (hl ? wl : wh)[(ks * 16 + 0) * 64 + ln];
    }
    __syncthreads();

    for (int n = 0; n < 16; ++n) {
        int cur = n & 1, nxt = cur ^ 1;
        uint4 pre[4];
        if (n < 15) {
            #pragma unroll
            for (int j = 0; j < 4; ++j) {
                int idx = j * 256 + t;
                int ks = idx >> 7, hl = (idx >> 6) & 1, ln = idx & 63;
                pre[j] = (hl ? wl : wh)[(ks * 16 + (n + 1)) * 64 + ln];
            }
        }
        if (active) {
            f4 c = {0.f, 0.f, 0.f, 0.f};
            #pragma unroll
            for (int ks = 0; ks < 8; ++ks) {
                bf8 bh = *(bf8*)&lbuf[cur][ks * 128 + lane];
                bf8 bl = *(bf8*)&lbuf[cur][ks * 128 + 64 + lane];
                c = __builtin_amdgcn_mfma_f32_16x16x32_bf16(ah[ks], bh, c, 0, 0, 0);
                c = __builtin_amdgcn_mfma_f32_16x16x32_bf16(al[ks], bh, c, 0, 0, 0);
                c = __builtin_amdgcn_mfma_f32_16x16x32_bf16(ah[ks], bl, c, 0, 0, 0);
            }
            int col = n * 16 + m;
            float bb = b[col];
            #pragma unroll
            for (int reg = 0; reg < 4; ++reg) {
                float v = c[reg] + bb;            // (r0+quad*4+reg, col)
                float o = __shfl_xor(v, 1, 64);   // partner column col^1
                if ((m & 1) == 0) {
                    hp[(r0 + quad * 4 + reg) * DH + (col >> 1)] = pack_bf2(v, o);
                }
            }
        }
        if (n < 15) {
            __syncthreads();                      // all done reading lbuf[nxt] (iter n-1)
            #pragma unroll
            for (int j = 0; j < 4; ++j) lbuf[nxt][j * 256 + t] = pre[j];
            __syncthreads();
        }
    }
}

// ---------------------------------------------------------------------------
// Gather one (row, adj, chunk) segment from packed-bf16 feature table.
// Thread tt in [0,128) owns features (2tt, 2tt+1).
// ---------------------------------------------------------------------------

__device__ __forceinline__ void gather_seg(const unsigned* __restrict__ E, int beg, int end,
                                           const unsigned* __restrict__ feat, int tt,
                                           float& s0, float& s1) {
    int e = beg;
    for (; e + 4 <= end; e += 4) {
        unsigned r0 = E[e], r1 = E[e + 1], r2 = E[e + 2], r3 = E[e + 3];
        unsigned p0 = feat[((r0 & 0xFFFFu) << 7) + tt];
        unsigned p1 = feat[((r1 & 0xFFFFu) << 7) + tt];
        unsigned p2 = feat[((r2 & 0xFFFFu) << 7) + tt];
        unsigned p3 = feat[((r3 & 0xFFFFu) << 7) + tt];
        float v0 = __uint_as_float(r0 & 0xFFFF0000u);
        float v1 = __uint_as_float(r1 & 0xFFFF0000u);
        float v2 = __uint_as_float(r2 & 0xFFFF0000u);
        float v3 = __uint_as_float(r3 & 0xFFFF0000u);
        s0 += v0 * bf_lo(p0); s1 += v0 * bf_hi(p0);
        s0 += v1 * bf_lo(p1); s1 += v1 * bf_hi(p1);
        s0 += v2 * bf_lo(p2); s1 += v2 * bf_hi(p2);
        s0 += v3 * bf_lo(p3); s1 += v3 * bf_hi(p3);
    }
    for (; e < end; ++e) {
        unsigned rr = E[e];
        unsigned pp = feat[((rr & 0xFFFFu) << 7) + tt];
        float vv = __uint_as_float(rr & 0xFFFF0000u);
        s0 += vv * bf_lo(pp); s1 += vv * bf_hi(pp);
    }
}

// ---------------------------------------------------------------------------
// Stage kernels: co-resident grid (NBLK blocks), each block owns <=6 row-pairs
// (p = blockIdx + k*NBLK), accumulators in registers, chunk loop outermost
// with soft grid alignment so every XCD's L2 holds exactly one 2.56MB chunk.
// ---------------------------------------------------------------------------

__global__ __launch_bounds__(256, 7) void stage1_kernel(const unsigned* __restrict__ hp,
                                                        const int* __restrict__ row_ptr,
                                                        const unsigned* __restrict__ csr,
                                                        const float* __restrict__ wseq0,
                                                        const float* __restrict__ wres0,
                                                        const float* __restrict__ wres1,
                                                        unsigned* __restrict__ s1p,
                                                        unsigned* __restrict__ s2p,
                                                        float2* __restrict__ outp,
                                                        int* __restrict__ bar) {
    int t = threadIdx.x, tt = t & 127, half = t >> 7;
    float acc[6][4][2];
    #pragma unroll
    for (int k = 0; k < 6; ++k)
        #pragma unroll
        for (int a = 0; a < 4; ++a) { acc[k][a][0] = 0.f; acc[k][a][1] = 0.f; }

    #pragma unroll 1
    for (int c = 0; c < NCHUNK; ++c) {
        if (c) soft_sync(bar, c);
        #pragma unroll
        for (int k = 0; k < 6; ++k) {
            int p = blockIdx.x + k * NBLK;
            if (p < 10000) {
                int r = 2 * p + half;
                #pragma unroll
                for (int a = 0; a < 4; ++a) {
                    const int* rp = row_ptr + (size_t)a * RPA + c * N_NODES;
                    gather_seg(csr + (size_t)a * N_EDGES, rp[r], rp[r + 1], hp, tt,
                               acc[k][a][0], acc[k][a][1]);
                }
            }
        }
    }
    float w0 = wseq0[0], w1 = wseq0[1], w2 = wseq0[2];
    float q0 = wres0[0], q1 = wres0[1], q2 = wres0[2], q3 = wres0[3];
    float u0 = wres1[0], u1 = wres1[1], u2 = wres1[2];
    const float third = 1.f / 3.f;
    #pragma unroll
    for (int k = 0; k < 6; ++k) {
        int p = blockIdx.x + k * NBLK;
        if (p < 10000) {
            int r = 2 * p + half, o = r * DH + tt;
            float s10 = (w0 * acc[k][0][0] + w1 * acc[k][1][0] + w2 * acc[k][2][0]) * third;
            float s11 = (w0 * acc[k][0][1] + w1 * acc[k][1][1] + w2 * acc[k][2][1]) * third;
            float s20 = (q0 * acc[k][0][0] + q1 * acc[k][1][0] + q2 * acc[k][2][0] + q3 * acc[k][3][0]) * 0.25f;
            float s21 = (q0 * acc[k][0][1] + q1 * acc[k][1][1] + q2 * acc[k][2][1] + q3 * acc[k][3][1]) * 0.25f;
            float o0  = (u0 * acc[k][0][0] + u1 * acc[k][1][0] + u2 * acc[k][3][0]) * third;
            float o1  = (u0 * acc[k][0][1] + u1 * acc[k][1][1] + u2 * acc[k][3][1]) * third;
            s1p[o]  = pack_bf2(s10, s11);
            s2p[o]  = pack_bf2(s20, s21);
            outp[o] = make_float2(o0, o1);
        }
    }
}

__global__ __launch_bounds__(256, 7) void stage2_kernel(const unsigned* __restrict__ s1p,
                                                        const int* __restrict__ row_ptr,
                                                        const unsigned* __restrict__ csr,
                                                        const float* __restrict__ wseq0,
                                                        const float* __restrict__ wres1,
                                                        unsigned* __restrict__ s2p,
                                                        float2* __restrict__ outp,
                                                        int* __restrict__ bar) {
    int t = threadIdx.x, tt = t & 127, half = t >> 7;
    float acc[6][4][2];
    #pragma unroll
    for (int k = 0; k < 6; ++k)
        #pragma unroll
        for (int a = 0; a < 4; ++a) { acc[k][a][0] = 0.f; acc[k][a][1] = 0.f; }

    #pragma unroll 1
    for (int c = 0; c < NCHUNK; ++c) {
        if (c) soft_sync(bar, c);
        #pragma unroll
        for (int k = 0; k < 6; ++k) {
            int p = blockIdx.x + k * NBLK;
            if (p < 10000) {
                int r = 2 * p + half;
                #pragma unroll
                for (int a = 0; a < 4; ++a) {
                    const int* rp = row_ptr + (size_t)a * RPA + c * N_NODES;
                    gather_seg(csr + (size_t)a * N_EDGES, rp[r], rp[r + 1], s1p, tt,
                               acc[k][a][0], acc[k][a][1]);
                }
            }
        }
    }
    float w3 = wseq0[3], w4 = wseq0[4], w5 = wseq0[5];
    float u3 = wres1[3], u4 = wres1[4], u5 = wres1[5];
    const float third = 1.f / 3.f;
    #pragma unroll
    for (int k = 0; k < 6; ++k) {
        int p = blockIdx.x + k * NBLK;
        if (p < 10000) {
            int r = 2 * p + half, o = r * DH + tt;
            unsigned sp = s2p[o];
            float c0 = bf_lo(sp) + (w3 * acc[k][0][0] + w4 * acc[k][1][0] + w5 * acc[k][2][0]) * third;
            float c1 = bf_hi(sp) + (w3 * acc[k][0][1] + w4 * acc[k][1][1] + w5 * acc[k][2][1]) * third;
            s2p[o] = pack_bf2(c0, c1);
            float2 op = outp[o];
            op.x += (u3 * acc[k][0][0] + u4 * acc[k][1][0] + u5 * acc[k][3][0]) * third;
            op.y += (u3 * acc[k][0][1] + u4 * acc[k][1][1] + u5 * acc[k][3][1]) * third;
            outp[o] = op;
        }
    }
}

__global__ __launch_bounds__(256, 7) void stage3_kernel(const unsigned* __restrict__ s2p,
                                                        const int* __restrict__ row_ptr,
                                                        const unsigned* __restrict__ csr,
                                                        const float* __restrict__ wseq1,
                                                        float2* __restrict__ outp,
                                                        int* __restrict__ bar) {
    int t = threadIdx.x, tt = t & 127, half = t >> 7;
    float acc[6][2][2];
    #pragma unroll
    for (int k = 0; k < 6; ++k)
        #pragma unroll
        for (int a = 0; a < 2; ++a) { acc[k][a][0] = 0.f; acc[k][a][1] = 0.f; }

    #pragma unroll 1
    for (int c = 0; c < NCHUNK; ++c) {
        if (c) soft_sync(bar, c);
        #pragma unroll
        for (int k = 0; k < 6; ++k) {
            int p = blockIdx.x + k * NBLK;
            if (p < 10000) {
                int r = 2 * p + half;
                #pragma unroll
                for (int a = 0; a < 2; ++a) {
                    const int* rp = row_ptr + (size_t)a * RPA + c * N_NODES;
                    gather_seg(csr + (size_t)a * N_EDGES, rp[r], rp[r + 1], s2p, tt,
                               acc[k][a][0], acc[k][a][1]);
                }
            }
        }
    }
    float e0 = wseq1[0] * 0.5f, e1 = wseq1[1] * 0.5f;
    __shared__ float sA[4], sB[4];
    int w = t >> 6, lane = t & 63;
    #pragma unroll
    for (int k = 0; k < 6; ++k) {
        int p = blockIdx.x + k * NBLK;
        if (p < 10000) {
            int r = 2 * p + half, o = r * DH + tt;
            float2 op = outp[o];
            float v0 = op.x + e0 * acc[k][0][0] + e1 * acc[k][1][0];
            float v1 = op.y + e0 * acc[k][0][1] + e1 * acc[k][1][1];
            float sv = v0 + v1, sq = v0 * v0 + v1 * v1;
            #pragma unroll
            for (int off = 32; off > 0; off >>= 1) {
                sv += __shfl_down(sv, off, 64);
                sq += __shfl_down(sq, off, 64);
            }
            __syncthreads();                 // protect sA/sB reuse across k
            if (lane == 0) { sA[w] = sv; sB[w] = sq; }
            __syncthreads();
            float sum  = sA[half * 2] + sA[half * 2 + 1];
            float sum2 = sB[half * 2] + sB[half * 2 + 1];
            float mu   = sum * (1.f / 256.f);
            float var  = sum2 * (1.f / 256.f) - mu * mu;
            float rstd = rsqrtf(var + 1e-5f);
            float y0 = (v0 - mu) * rstd;
            float y1 = (v1 - mu) * rstd;
            float g0 = 0.5f * y0 * (1.f + erff(y0 * 0.70710678118654752440f));
            float g1 = 0.5f * y1 * (1.f + erff(y1 * 0.70710678118654752440f));
            outp[o] = make_float2(g0, g1);
        }
    }
}

// ---------------------------------------------------------------------------

extern "C" void kernel_launch(void* const* d_in, const int* in_sizes, int n_in,
                              void* d_out, int out_size, void* d_ws, size_t ws_size,
                              hipStream_t stream) {
    const float* x     = (const float*)d_in[0];
    const int*   rows  = (const int*)d_in[1];
    const int*   cols  = (const int*)d_in[2];
    const float* vals  = (const float*)d_in[3];
    const float* W     = (const float*)d_in[4];
    const float* b     = (const float*)d_in[5];
    const float* wseq0 = (const float*)d_in[6];  // (2,3)
    const float* wseq1 = (const float*)d_in[7];  // (2,)
    const float* wres0 = (const float*)d_in[8];  // (1,4)
    const float* wres1 = (const float*)d_in[9];  // (2,3)
    float2* outp = (float2*)d_out;

    char* p = (char*)d_ws;
    unsigned* hp  = (unsigned*)p; p += (size_t)N_NODES * DH * 4;      // 10.24 MB
    unsigned* s1p = (unsigned*)p; p += (size_t)N_NODES * DH * 4;      // 10.24 MB
    unsigned* s2p = (unsigned*)p; p += (size_t)N_NODES * DH * 4;      // 10.24 MB
    int* row_ptr  = (int*)p;      p += (size_t)N_ADJ * RPA * 4;       // 1.28 MB
    int* cnt      = (int*)p;      p += (size_t)N_ADJ * 80000 * 4;     // 1.28 MB
    int* bar      = (int*)p;      p += 256;                           // 3 barrier counters
    int* work     = (int*)p;      p += (size_t)N_ADJ * 80000 * 4;     // 1.28 MB
    uint4* wh     = (uint4*)p;    p += 8192 * 16;                     // 128 KB
    uint4* wl     = (uint4*)p;    p += 8192 * 16;                     // 128 KB
    unsigned* csr = (unsigned*)p;                                     // 5.12 MB

    // zero cnt + bar in one shot (they are adjacent)
    hipMemsetAsync(cnt, 0, (size_t)N_ADJ * 80000 * 4 + 256, stream);

    dim3 egrid((N_EDGES + 255) / 256, N_ADJ);
    hist_kernel<<<egrid, 256, 0, stream>>>(rows, cols, cnt);
    scan_kernel<<<N_ADJ, 1024, 0, stream>>>((const int4*)cnt, row_ptr, work);
    scatter_kernel<<<egrid, 256, 0, stream>>>(rows, cols, vals, work, csr);

    wfrag_kernel<<<32, 256, 0, stream>>>(W, wh, wl);
    mfma_matmul_kernel<<<313, 256, 0, stream>>>(x, wh, wl, b, hp);

    stage1_kernel<<<NBLK, 256, 0, stream>>>(hp, row_ptr, csr, wseq0, wres0, wres1,
                                            s1p, s2p, outp, bar + 0);
    stage2_kernel<<<NBLK, 256, 0, stream>>>(s1p, row_ptr, csr, wseq0, wres1,
                                            s2p, outp, bar + 16);
    stage3_kernel<<<NBLK, 256, 0, stream>>>(s2p, row_ptr, csr, wseq1, outp, bar + 32);
}

// Round 5
// 514.541 us; speedup vs baseline: 9.5324x; 9.5324x over previous
//
#include <hip/hip_runtime.h>
#include <hip/hip_bf16.h>

#define N_NODES 20000
#define N_EDGES 320000
#define N_ADJ   4
#define D       256
#define DH      128              // packed bf16x2 dwords per feature row
#define RPA     20004            // row_ptr stride per adjacency (20001 rounded to x4)

typedef __attribute__((ext_vector_type(8))) short bf8;   // 8 bf16 (4 VGPRs)
typedef __attribute__((ext_vector_type(4))) float f4;    // MFMA accumulator

// ---------------------------------------------------------------------------
// bf16 pack/unpack helpers (RNE rounding; values are finite)
// ---------------------------------------------------------------------------

__device__ __forceinline__ unsigned f2bf_bits(float x) {
    unsigned u = __float_as_uint(x);
    return (u + 0x7FFFu + ((u >> 16) & 1u)) >> 16;
}
__device__ __forceinline__ unsigned pack_bf2(float lo, float hi) {
    return f2bf_bits(lo) | (f2bf_bits(hi) << 16);
}
__device__ __forceinline__ float bf_lo(unsigned p) { return __uint_as_float(p << 16); }
__device__ __forceinline__ float bf_hi(unsigned p) { return __uint_as_float(p & 0xFFFF0000u); }

// ---------------------------------------------------------------------------
// CSR build: histogram -> exclusive scan -> scatter.
// Edge record: 32 bits = (bf16(val) << 16) | col   (col < 20000 < 2^16).
// ---------------------------------------------------------------------------

__global__ __launch_bounds__(256) void hist_kernel(const int* __restrict__ rows,
                                                   int* __restrict__ cnt) {
    int e = blockIdx.x * 256 + threadIdx.x;
    int a = blockIdx.y;
    if (e < N_EDGES) {
        atomicAdd(&cnt[a * N_NODES + rows[a * N_EDGES + e]], 1);
    }
}

// 4 blocks x 1024 thr; 4 ints/thread via int4; shuffle wave scans.
__global__ __launch_bounds__(1024) void scan_kernel(const int4* __restrict__ cnt4,
                                                    int* __restrict__ row_ptr,
                                                    int* __restrict__ work) {
    int a = blockIdx.x, t = threadIdx.x;
    int lane = t & 63, w = t >> 6;            // 16 waves
    __shared__ int wsum[16];
    const int4* src = cnt4 + (size_t)a * 5000;       // 20000 ints = 5000 int4
    int4* rp4 = (int4*)(row_ptr + (size_t)a * RPA);
    int4* wk4 = (int4*)(work + (size_t)a * N_NODES);
    int carry = 0;
    for (int base = 0; base < 5000; base += 1024) {
        int i = base + t;
        int4 v = (i < 5000) ? src[i] : make_int4(0, 0, 0, 0);
        int tsum = v.x + v.y + v.z + v.w;
        int s = tsum;                          // inclusive wave scan of thread sums
        #pragma unroll
        for (int off = 1; off < 64; off <<= 1) {
            int u = __shfl_up(s, off, 64);
            if (lane >= off) s += u;
        }
        if (lane == 63) wsum[w] = s;
        __syncthreads();
        int woff = 0, total = 0;
        #pragma unroll
        for (int j = 0; j < 16; ++j) {
            int ws = wsum[j];
            woff  += (j < w) ? ws : 0;
            total += ws;
        }
        __syncthreads();
        if (i < 5000) {
            int excl = carry + woff + s - tsum;
            int4 o;
            o.x = excl; o.y = excl + v.x; o.z = o.y + v.y; o.w = o.z + v.z;
            rp4[i] = o;
            wk4[i] = o;
        }
        carry += total;
    }
    if (t == 0) row_ptr[(size_t)a * RPA + N_NODES] = carry;
}

__global__ __launch_bounds__(256) void scatter_kernel(const int* __restrict__ rows,
                                                      const int* __restrict__ cols,
                                                      const float* __restrict__ vals,
                                                      int* __restrict__ work,
                                                      unsigned* __restrict__ csr) {
    int e = blockIdx.x * 256 + threadIdx.x;
    int a = blockIdx.y;
    if (e < N_EDGES) {
        int r   = rows[a * N_EDGES + e];
        int idx = atomicAdd(&work[a * N_NODES + r], 1);
        csr[(size_t)a * N_EDGES + idx] =
            (f2bf_bits(vals[a * N_EDGES + e]) << 16) | (unsigned)cols[a * N_EDGES + e];
    }
}

// ---------------------------------------------------------------------------
// W -> fragment-ordered bf16 hi/lo tables (one uint4 per lane per (ks,n) tile).
// B frag layout (16x16x32): n_idx = lane&15, k = ks*32 + (lane>>4)*8 + j.
// ---------------------------------------------------------------------------

__global__ __launch_bounds__(256) void wfrag_kernel(const float* __restrict__ W,
                                                    uint4* __restrict__ wh,
                                                    uint4* __restrict__ wl) {
    int g = blockIdx.x * 256 + threadIdx.x;   // 0..8191 = (ks*16+n)*64 + lane
    int lane = g & 63;
    int tile = g >> 6;                        // ks*16 + n
    int ks = tile >> 4, n = tile & 15;
    int m = lane & 15, quad = lane >> 4;
    int col = n * 16 + m;
    int k0  = ks * 32 + quad * 8;
    unsigned hbits[8], lbits[8];
    #pragma unroll
    for (int j = 0; j < 8; ++j) {
        float v = W[(k0 + j) * D + col];
        unsigned hb = f2bf_bits(v);
        float lo = v - __uint_as_float(hb << 16);
        hbits[j] = hb;
        lbits[j] = f2bf_bits(lo);
    }
    uint4 hh, ll;
    hh.x = hbits[0] | (hbits[1] << 16); hh.y = hbits[2] | (hbits[3] << 16);
    hh.z = hbits[4] | (hbits[5] << 16); hh.w = hbits[6] | (hbits[7] << 16);
    ll.x = lbits[0] | (lbits[1] << 16); ll.y = lbits[2] | (lbits[3] << 16);
    ll.z = lbits[4] | (lbits[5] << 16); ll.w = lbits[6] | (lbits[7] << 16);
    wh[g] = hh;
    wl[g] = ll;
}

// ---------------------------------------------------------------------------
// h = x @ W + b via bf16 MFMA hi/lo compensation (f32-accurate).  Block =
// 4 waves = 4 row tiles; B frags staged via double-buffered LDS.
// ---------------------------------------------------------------------------

__global__ __launch_bounds__(256) void mfma_matmul_kernel(const float* __restrict__ x,
                                                          const uint4* __restrict__ wh,
                                                          const uint4* __restrict__ wl,
                                                          const float* __restrict__ b,
                                                          unsigned* __restrict__ hp) {
    __shared__ uint4 lbuf[2][1024];           // [buf][ks*128 + hl*64 + lane], 32 KB
    int t = threadIdx.x, wid = t >> 6, lane = t & 63;
    int r0 = (blockIdx.x * 4 + wid) * 16;
    bool active = r0 < N_NODES;
    int m = lane & 15, quad = lane >> 4;

    bf8 ah[8], al[8];
    if (active) {
        const float* xr = x + (size_t)(r0 + m) * D + quad * 8;
        #pragma unroll
        for (int ks = 0; ks < 8; ++ks) {
            float4 v0 = *(const float4*)(xr + ks * 32);
            float4 v1 = *(const float4*)(xr + ks * 32 + 4);
            float xs[8] = {v0.x, v0.y, v0.z, v0.w, v1.x, v1.y, v1.z, v1.w};
            #pragma unroll
            for (int j = 0; j < 8; ++j) {
                unsigned hb = f2bf_bits(xs[j]);
                float lo = xs[j] - __uint_as_float(hb << 16);
                ah[ks][j] = (short)hb;
                al[ks][j] = (short)f2bf_bits(lo);
            }
        }
    }

    // prologue: stage n=0 fragments
    #pragma unroll
    for (int j = 0; j < 4; ++j) {
        int idx = j * 256 + t;
        int ks = idx >> 7, hl = (idx >> 6) & 1, ln = idx & 63;
        lbuf[0][idx] = (hl ? wl : wh)[(ks * 16 + 0) * 64 + ln];
    }
    __syncthreads();

    for (int n = 0; n < 16; ++n) {
        int cur = n & 1, nxt = cur ^ 1;
        uint4 pre[4];
        if (n < 15) {
            #pragma unroll
            for (int j = 0; j < 4; ++j) {
                int idx = j * 256 + t;
                int ks = idx >> 7, hl = (idx >> 6) & 1, ln = idx & 63;
                pre[j] = (hl ? wl : wh)[(ks * 16 + (n + 1)) * 64 + ln];
            }
        }
        if (active) {
            f4 c = {0.f, 0.f, 0.f, 0.f};
            #pragma unroll
            for (int ks = 0; ks < 8; ++ks) {
                bf8 bh = *(bf8*)&lbuf[cur][ks * 128 + lane];
                bf8 bl = *(bf8*)&lbuf[cur][ks * 128 + 64 + lane];
                c = __builtin_amdgcn_mfma_f32_16x16x32_bf16(ah[ks], bh, c, 0, 0, 0);
                c = __builtin_amdgcn_mfma_f32_16x16x32_bf16(al[ks], bh, c, 0, 0, 0);
                c = __builtin_amdgcn_mfma_f32_16x16x32_bf16(ah[ks], bl, c, 0, 0, 0);
            }
            int col = n * 16 + m;
            float bb = b[col];
            #pragma unroll
            for (int reg = 0; reg < 4; ++reg) {
                float v = c[reg] + bb;            // (r0+quad*4+reg, col)
                float o = __shfl_xor(v, 1, 64);   // partner column col^1
                if ((m & 1) == 0) {
                    hp[(r0 + quad * 4 + reg) * DH + (col >> 1)] = pack_bf2(v, o);
                }
            }
        }
        if (n < 15) {
            __syncthreads();                      // all done reading lbuf[nxt]
            #pragma unroll
            for (int j = 0; j < 4; ++j) lbuf[nxt][j * 256 + t] = pre[j];
            __syncthreads();
        }
    }
}

// ---------------------------------------------------------------------------
// Gather one (row, adj) segment from packed-bf16 feature table.
// Thread tt in [0,128) owns features (2tt, 2tt+1).  8-deep software pipeline:
// next iteration's edge records (wave-uniform -> scalar loads) prefetched
// under the current iteration's feature loads + FMAs.
// ---------------------------------------------------------------------------

__device__ __forceinline__ void gather_seg(const unsigned* __restrict__ E, int beg, int end,
                                           const unsigned* __restrict__ feat, int tt,
                                           float& s0, float& s1) {
    int n = end - beg;
    const unsigned* e = E + beg;
    int m8 = n & ~7;
    if (m8) {
        unsigned rec[8];
        #pragma unroll
        for (int j = 0; j < 8; ++j) rec[j] = e[j];
        for (int i = 8; ; i += 8) {
            unsigned p[8];
            #pragma unroll
            for (int j = 0; j < 8; ++j) p[j] = feat[((rec[j] & 0xFFFFu) << 7) + tt];
            bool more = i < m8;
            unsigned nrec[8];
            if (more) {
                #pragma unroll
                for (int j = 0; j < 8; ++j) nrec[j] = e[i + j];
            }
            #pragma unroll
            for (int j = 0; j < 8; ++j) {
                float v = __uint_as_float(rec[j] & 0xFFFF0000u);
                s0 += v * bf_lo(p[j]);
                s1 += v * bf_hi(p[j]);
            }
            if (!more) break;
            #pragma unroll
            for (int j = 0; j < 8; ++j) rec[j] = nrec[j];
        }
    }
    for (int i = m8; i < n; ++i) {
        unsigned rr = e[i];
        unsigned pp = feat[((rr & 0xFFFFu) << 7) + tt];
        float vv = __uint_as_float(rr & 0xFFFF0000u);
        s0 += vv * bf_lo(pp); s1 += vv * bf_hi(pp);
    }
}

// ---------------------------------------------------------------------------
// Stage 1: input h (packed).  Emits s1, s2-partial (packed), out-partial
// (f32, into d_out).  2 rows per block: threads 0-127 row 2b, 128-255 row 2b+1.
// ---------------------------------------------------------------------------

__global__ __launch_bounds__(256) void stage1_kernel(const unsigned* __restrict__ hp,
                                                     const int* __restrict__ row_ptr,
                                                     const unsigned* __restrict__ csr,
                                                     const float* __restrict__ wseq0,
                                                     const float* __restrict__ wres0,
                                                     const float* __restrict__ wres1,
                                                     unsigned* __restrict__ s1p,
                                                     unsigned* __restrict__ s2p,
                                                     float2* __restrict__ outp) {
    int t = threadIdx.x, tt = t & 127;
    int r = blockIdx.x * 2 + (t >> 7);
    float a0[N_ADJ], a1[N_ADJ];
    #pragma unroll
    for (int a = 0; a < N_ADJ; ++a) {
        a0[a] = 0.f; a1[a] = 0.f;
        const int* rp = row_ptr + (size_t)a * RPA;
        gather_seg(csr + (size_t)a * N_EDGES, rp[r], rp[r + 1], hp, tt, a0[a], a1[a]);
    }
    const float third = 1.f / 3.f;
    float s1v0 = (wseq0[0] * a0[0] + wseq0[1] * a0[1] + wseq0[2] * a0[2]) * third;
    float s1v1 = (wseq0[0] * a1[0] + wseq0[1] * a1[1] + wseq0[2] * a1[2]) * third;
    float s2v0 = (wres0[0] * a0[0] + wres0[1] * a0[1] + wres0[2] * a0[2] + wres0[3] * a0[3]) * 0.25f;
    float s2v1 = (wres0[0] * a1[0] + wres0[1] * a1[1] + wres0[2] * a1[2] + wres0[3] * a1[3]) * 0.25f;
    float ov0  = (wres1[0] * a0[0] + wres1[1] * a0[1] + wres1[2] * a0[3]) * third;
    float ov1  = (wres1[0] * a1[0] + wres1[1] * a1[1] + wres1[2] * a1[3]) * third;
    int o = r * DH + tt;
    s1p[o]  = pack_bf2(s1v0, s1v1);
    s2p[o]  = pack_bf2(s2v0, s2v1);
    outp[o] = make_float2(ov0, ov1);
}

// ---------------------------------------------------------------------------
// Stage 2: input s1 (packed).  s2 += seq-combo; out-partial += res-combo.
// ---------------------------------------------------------------------------

__global__ __launch_bounds__(256) void stage2_kernel(const unsigned* __restrict__ s1p,
                                                     const int* __restrict__ row_ptr,
                                                     const unsigned* __restrict__ csr,
                                                     const float* __restrict__ wseq0,
                                                     const float* __restrict__ wres1,
                                                     unsigned* __restrict__ s2p,
                                                     float2* __restrict__ outp) {
    int t = threadIdx.x, tt = t & 127;
    int r = blockIdx.x * 2 + (t >> 7);
    float a0[N_ADJ], a1[N_ADJ];
    #pragma unroll
    for (int a = 0; a < N_ADJ; ++a) {
        a0[a] = 0.f; a1[a] = 0.f;
        const int* rp = row_ptr + (size_t)a * RPA;
        gather_seg(csr + (size_t)a * N_EDGES, rp[r], rp[r + 1], s1p, tt, a0[a], a1[a]);
    }
    const float third = 1.f / 3.f;
    int o = r * DH + tt;
    unsigned sp = s2p[o];
    float c0 = bf_lo(sp) + (wseq0[3] * a0[0] + wseq0[4] * a0[1] + wseq0[5] * a0[2]) * third;
    float c1 = bf_hi(sp) + (wseq0[3] * a1[0] + wseq0[4] * a1[1] + wseq0[5] * a1[2]) * third;
    s2p[o] = pack_bf2(c0, c1);
    float2 op = outp[o];
    op.x += (wres1[3] * a0[0] + wres1[4] * a0[1] + wres1[5] * a0[3]) * third;
    op.y += (wres1[3] * a1[0] + wres1[4] * a1[1] + wres1[5] * a1[3]) * third;
    outp[o] = op;
}

// ---------------------------------------------------------------------------
// Stage 3: input s2 (adjacencies 0,1), add out-partial, LayerNorm, exact GELU.
// ---------------------------------------------------------------------------

__global__ __launch_bounds__(256) void stage3_kernel(const unsigned* __restrict__ s2p,
                                                     const int* __restrict__ row_ptr,
                                                     const unsigned* __restrict__ csr,
                                                     const float* __restrict__ wseq1,
                                                     float2* __restrict__ outp) {
    int t = threadIdx.x, tt = t & 127, half = t >> 7;
    int r = blockIdx.x * 2 + half;
    float a0[2], a1[2];
    #pragma unroll
    for (int a = 0; a < 2; ++a) {
        a0[a] = 0.f; a1[a] = 0.f;
        const int* rp = row_ptr + (size_t)a * RPA;
        gather_seg(csr + (size_t)a * N_EDGES, rp[r], rp[r + 1], s2p, tt, a0[a], a1[a]);
    }
    int o = r * DH + tt;
    float2 op = outp[o];
    float val0 = op.x + (wseq1[0] * a0[0] + wseq1[1] * a0[1]) * 0.5f;
    float val1 = op.y + (wseq1[0] * a1[0] + wseq1[1] * a1[1]) * 0.5f;

    // LayerNorm over 256 features = 2 values x 128 threads (2 waves per row)
    float v = val0 + val1, v2 = val0 * val0 + val1 * val1;
    #pragma unroll
    for (int off = 32; off > 0; off >>= 1) {
        v  += __shfl_down(v, off, 64);
        v2 += __shfl_down(v2, off, 64);
    }
    __shared__ float sA[4], sB[4];
    int w = t >> 6, lane = t & 63;
    if (lane == 0) { sA[w] = v; sB[w] = v2; }
    __syncthreads();
    float sum  = sA[half * 2] + sA[half * 2 + 1];
    float sum2 = sB[half * 2] + sB[half * 2 + 1];
    float mu   = sum * (1.f / 256.f);
    float var  = sum2 * (1.f / 256.f) - mu * mu;
    float rstd = rsqrtf(var + 1e-5f);
    float y0   = (val0 - mu) * rstd;
    float y1   = (val1 - mu) * rstd;
    float g0 = 0.5f * y0 * (1.f + erff(y0 * 0.70710678118654752440f));
    float g1 = 0.5f * y1 * (1.f + erff(y1 * 0.70710678118654752440f));
    outp[o] = make_float2(g0, g1);
}

// ---------------------------------------------------------------------------

extern "C" void kernel_launch(void* const* d_in, const int* in_sizes, int n_in,
                              void* d_out, int out_size, void* d_ws, size_t ws_size,
                              hipStream_t stream) {
    const float* x     = (const float*)d_in[0];
    const int*   rows  = (const int*)d_in[1];
    const int*   cols  = (const int*)d_in[2];
    const float* vals  = (const float*)d_in[3];
    const float* W     = (const float*)d_in[4];
    const float* b     = (const float*)d_in[5];
    const float* wseq0 = (const float*)d_in[6];  // (2,3)
    const float* wseq1 = (const float*)d_in[7];  // (2,)
    const float* wres0 = (const float*)d_in[8];  // (1,4)
    const float* wres1 = (const float*)d_in[9];  // (2,3)
    float2* outp = (float2*)d_out;

    char* p = (char*)d_ws;
    unsigned* hp  = (unsigned*)p; p += (size_t)N_NODES * DH * 4;      // 10.24 MB
    unsigned* s1p = (unsigned*)p; p += (size_t)N_NODES * DH * 4;      // 10.24 MB
    unsigned* s2p = (unsigned*)p; p += (size_t)N_NODES * DH * 4;      // 10.24 MB
    int* row_ptr  = (int*)p;      p += (size_t)N_ADJ * RPA * 4;       // 320 KB
    int* cnt      = (int*)p;      p += (size_t)N_ADJ * N_NODES * 4;   // 320 KB
    int* work     = (int*)p;      p += (size_t)N_ADJ * N_NODES * 4;   // 320 KB
    uint4* wh     = (uint4*)p;    p += 8192 * 16;                     // 128 KB
    uint4* wl     = (uint4*)p;    p += 8192 * 16;                     // 128 KB
    unsigned* csr = (unsigned*)p;                                     // 5.12 MB

    hipMemsetAsync(cnt, 0, (size_t)N_ADJ * N_NODES * sizeof(int), stream);

    dim3 egrid((N_EDGES + 255) / 256, N_ADJ);
    hist_kernel<<<egrid, 256, 0, stream>>>(rows, cnt);
    scan_kernel<<<N_ADJ, 1024, 0, stream>>>((const int4*)cnt, row_ptr, work);
    scatter_kernel<<<egrid, 256, 0, stream>>>(rows, cols, vals, work, csr);

    wfrag_kernel<<<32, 256, 0, stream>>>(W, wh, wl);
    mfma_matmul_kernel<<<313, 256, 0, stream>>>(x, wh, wl, b, hp);

    stage1_kernel<<<N_NODES / 2, 256, 0, stream>>>(hp, row_ptr, csr, wseq0, wres0,
                                                   wres1, s1p, s2p, outp);
    stage2_kernel<<<N_NODES / 2, 256, 0, stream>>>(s1p, row_ptr, csr, wseq0, wres1,
                                                   s2p, outp);
    stage3_kernel<<<N_NODES / 2, 256, 0, stream>>>(s2p, row_ptr, csr, wseq1, outp);
}

// Round 6
// 455.826 us; speedup vs baseline: 10.7602x; 1.1288x over previous
//
#include <hip/hip_runtime.h>
#include <hip/hip_bf16.h>

#define N_NODES 20000
#define N_EDGES 320000
#define N_ADJ   4
#define D       256
#define DH      128              // packed bf16x2 dwords per feature row
#define RPA     20004            // row_ptr stride per adjacency (20001 rounded to x4)

typedef __attribute__((ext_vector_type(8))) short bf8;   // 8 bf16 (4 VGPRs)
typedef __attribute__((ext_vector_type(4))) float f4;    // MFMA accumulator

// ---------------------------------------------------------------------------
// bf16 pack/unpack helpers (RNE rounding; values are finite)
// ---------------------------------------------------------------------------

__device__ __forceinline__ unsigned f2bf_bits(float x) {
    unsigned u = __float_as_uint(x);
    return (u + 0x7FFFu + ((u >> 16) & 1u)) >> 16;
}
__device__ __forceinline__ unsigned pack_bf2(float lo, float hi) {
    return f2bf_bits(lo) | (f2bf_bits(hi) << 16);
}
__device__ __forceinline__ float bf_lo(unsigned p) { return __uint_as_float(p << 16); }
__device__ __forceinline__ float bf_hi(unsigned p) { return __uint_as_float(p & 0xFFFF0000u); }

// ---------------------------------------------------------------------------
// CSR build: histogram -> exclusive scan -> scatter.
// Edge record: 32 bits = (bf16(val) << 16) | col   (col < 20000 < 2^16).
// ---------------------------------------------------------------------------

__global__ __launch_bounds__(256) void hist_kernel(const int* __restrict__ rows,
                                                   int* __restrict__ cnt) {
    int e = blockIdx.x * 256 + threadIdx.x;
    int a = blockIdx.y;
    if (e < N_EDGES) {
        atomicAdd(&cnt[a * N_NODES + rows[a * N_EDGES + e]], 1);
    }
}

// 4 blocks x 1024 thr; 4 ints/thread via int4; shuffle wave scans.
__global__ __launch_bounds__(1024) void scan_kernel(const int4* __restrict__ cnt4,
                                                    int* __restrict__ row_ptr,
                                                    int* __restrict__ work) {
    int a = blockIdx.x, t = threadIdx.x;
    int lane = t & 63, w = t >> 6;            // 16 waves
    __shared__ int wsum[16];
    const int4* src = cnt4 + (size_t)a * 5000;       // 20000 ints = 5000 int4
    int4* rp4 = (int4*)(row_ptr + (size_t)a * RPA);
    int4* wk4 = (int4*)(work + (size_t)a * N_NODES);
    int carry = 0;
    for (int base = 0; base < 5000; base += 1024) {
        int i = base + t;
        int4 v = (i < 5000) ? src[i] : make_int4(0, 0, 0, 0);
        int tsum = v.x + v.y + v.z + v.w;
        int s = tsum;                          // inclusive wave scan of thread sums
        #pragma unroll
        for (int off = 1; off < 64; off <<= 1) {
            int u = __shfl_up(s, off, 64);
            if (lane >= off) s += u;
        }
        if (lane == 63) wsum[w] = s;
        __syncthreads();
        int woff = 0, total = 0;
        #pragma unroll
        for (int j = 0; j < 16; ++j) {
            int ws = wsum[j];
            woff  += (j < w) ? ws : 0;
            total += ws;
        }
        __syncthreads();
        if (i < 5000) {
            int excl = carry + woff + s - tsum;
            int4 o;
            o.x = excl; o.y = excl + v.x; o.z = o.y + v.y; o.w = o.z + v.z;
            rp4[i] = o;
            wk4[i] = o;
        }
        carry += total;
    }
    if (t == 0) row_ptr[(size_t)a * RPA + N_NODES] = carry;
}

__global__ __launch_bounds__(256) void scatter_kernel(const int* __restrict__ rows,
                                                      const int* __restrict__ cols,
                                                      const float* __restrict__ vals,
                                                      int* __restrict__ work,
                                                      unsigned* __restrict__ csr) {
    int e = blockIdx.x * 256 + threadIdx.x;
    int a = blockIdx.y;
    if (e < N_EDGES) {
        int r   = rows[a * N_EDGES + e];
        int idx = atomicAdd(&work[a * N_NODES + r], 1);
        csr[(size_t)a * N_EDGES + idx] =
            (f2bf_bits(vals[a * N_EDGES + e]) << 16) | (unsigned)cols[a * N_EDGES + e];
    }
}

// ---------------------------------------------------------------------------
// W -> fragment-ordered bf16 hi/lo tables (one uint4 per lane per (ks,n) tile).
// B frag layout (16x16x32): n_idx = lane&15, k = ks*32 + (lane>>4)*8 + j.
// ---------------------------------------------------------------------------

__global__ __launch_bounds__(256) void wfrag_kernel(const float* __restrict__ W,
                                                    uint4* __restrict__ wh,
                                                    uint4* __restrict__ wl) {
    int g = blockIdx.x * 256 + threadIdx.x;   // 0..8191 = (ks*16+n)*64 + lane
    int lane = g & 63;
    int tile = g >> 6;                        // ks*16 + n
    int ks = tile >> 4, n = tile & 15;
    int m = lane & 15, quad = lane >> 4;
    int col = n * 16 + m;
    int k0  = ks * 32 + quad * 8;
    unsigned hbits[8], lbits[8];
    #pragma unroll
    for (int j = 0; j < 8; ++j) {
        float v = W[(k0 + j) * D + col];
        unsigned hb = f2bf_bits(v);
        float lo = v - __uint_as_float(hb << 16);
        hbits[j] = hb;
        lbits[j] = f2bf_bits(lo);
    }
    uint4 hh, ll;
    hh.x = hbits[0] | (hbits[1] << 16); hh.y = hbits[2] | (hbits[3] << 16);
    hh.z = hbits[4] | (hbits[5] << 16); hh.w = hbits[6] | (hbits[7] << 16);
    ll.x = lbits[0] | (lbits[1] << 16); ll.y = lbits[2] | (lbits[3] << 16);
    ll.z = lbits[4] | (lbits[5] << 16); ll.w = lbits[6] | (lbits[7] << 16);
    wh[g] = hh;
    wl[g] = ll;
}

// ---------------------------------------------------------------------------
// h = x @ W + b via bf16 MFMA hi/lo compensation (f32-accurate).  Block =
// 4 waves = 4 row tiles; B frags staged via double-buffered LDS.
// ---------------------------------------------------------------------------

__global__ __launch_bounds__(256) void mfma_matmul_kernel(const float* __restrict__ x,
                                                          const uint4* __restrict__ wh,
                                                          const uint4* __restrict__ wl,
                                                          const float* __restrict__ b,
                                                          unsigned* __restrict__ hp) {
    __shared__ uint4 lbuf[2][1024];           // [buf][ks*128 + hl*64 + lane], 32 KB
    int t = threadIdx.x, wid = t >> 6, lane = t & 63;
    int r0 = (blockIdx.x * 4 + wid) * 16;
    bool active = r0 < N_NODES;
    int m = lane & 15, quad = lane >> 4;

    bf8 ah[8], al[8];
    if (active) {
        const float* xr = x + (size_t)(r0 + m) * D + quad * 8;
        #pragma unroll
        for (int ks = 0; ks < 8; ++ks) {
            float4 v0 = *(const float4*)(xr + ks * 32);
            float4 v1 = *(const float4*)(xr + ks * 32 + 4);
            float xs[8] = {v0.x, v0.y, v0.z, v0.w, v1.x, v1.y, v1.z, v1.w};
            #pragma unroll
            for (int j = 0; j < 8; ++j) {
                unsigned hb = f2bf_bits(xs[j]);
                float lo = xs[j] - __uint_as_float(hb << 16);
                ah[ks][j] = (short)hb;
                al[ks][j] = (short)f2bf_bits(lo);
            }
        }
    }

    // prologue: stage n=0 fragments
    #pragma unroll
    for (int j = 0; j < 4; ++j) {
        int idx = j * 256 + t;
        int ks = idx >> 7, hl = (idx >> 6) & 1, ln = idx & 63;
        lbuf[0][idx] = (hl ? wl : wh)[(ks * 16 + 0) * 64 + ln];
    }
    __syncthreads();

    for (int n = 0; n < 16; ++n) {
        int cur = n & 1, nxt = cur ^ 1;
        uint4 pre[4];
        if (n < 15) {
            #pragma unroll
            for (int j = 0; j < 4; ++j) {
                int idx = j * 256 + t;
                int ks = idx >> 7, hl = (idx >> 6) & 1, ln = idx & 63;
                pre[j] = (hl ? wl : wh)[(ks * 16 + (n + 1)) * 64 + ln];
            }
        }
        if (active) {
            f4 c = {0.f, 0.f, 0.f, 0.f};
            #pragma unroll
            for (int ks = 0; ks < 8; ++ks) {
                bf8 bh = *(bf8*)&lbuf[cur][ks * 128 + lane];
                bf8 bl = *(bf8*)&lbuf[cur][ks * 128 + 64 + lane];
                c = __builtin_amdgcn_mfma_f32_16x16x32_bf16(ah[ks], bh, c, 0, 0, 0);
                c = __builtin_amdgcn_mfma_f32_16x16x32_bf16(al[ks], bh, c, 0, 0, 0);
                c = __builtin_amdgcn_mfma_f32_16x16x32_bf16(ah[ks], bl, c, 0, 0, 0);
            }
            int col = n * 16 + m;
            float bb = b[col];
            #pragma unroll
            for (int reg = 0; reg < 4; ++reg) {
                float v = c[reg] + bb;            // (r0+quad*4+reg, col)
                float o = __shfl_xor(v, 1, 64);   // partner column col^1
                if ((m & 1) == 0) {
                    hp[(r0 + quad * 4 + reg) * DH + (col >> 1)] = pack_bf2(v, o);
                }
            }
        }
        if (n < 15) {
            __syncthreads();                      // all done reading lbuf[nxt]
            #pragma unroll
            for (int j = 0; j < 4; ++j) lbuf[nxt][j * 256 + t] = pre[j];
            __syncthreads();
        }
    }
}

// ---------------------------------------------------------------------------
// Gather one (row, adj) segment.  ONE WAVE per row: lane owns features
// 4*lane..4*lane+3 (one uint2 = 2 packed dwords).  beg/end are wave-uniform
// (readfirstlane'd by caller) so edge records + val stay in SGPRs; the VALU
// path per edge is 1 dwordx2 load + 4 unpack + 4 FMA.  8-deep pipeline.
// ---------------------------------------------------------------------------

__device__ __forceinline__ void gather_seg(const unsigned* __restrict__ E, int beg, int end,
                                           const uint2* __restrict__ feat2, int lane,
                                           float* __restrict__ s /* [4] */) {
    int n = end - beg;
    const unsigned* e = E + beg;
    int m8 = n & ~7;
    if (m8) {
        unsigned rec[8];
        #pragma unroll
        for (int j = 0; j < 8; ++j) rec[j] = e[j];
        for (int i = 8; ; i += 8) {
            uint2 p[8];
            #pragma unroll
            for (int j = 0; j < 8; ++j)
                p[j] = feat2[((rec[j] & 0xFFFFu) << 6) + lane];
            bool more = i < m8;
            unsigned nrec[8];
            if (more) {
                #pragma unroll
                for (int j = 0; j < 8; ++j) nrec[j] = e[i + j];
            }
            #pragma unroll
            for (int j = 0; j < 8; ++j) {
                float v = __uint_as_float(rec[j] & 0xFFFF0000u);
                s[0] += v * bf_lo(p[j].x);
                s[1] += v * bf_hi(p[j].x);
                s[2] += v * bf_lo(p[j].y);
                s[3] += v * bf_hi(p[j].y);
            }
            if (!more) break;
            #pragma unroll
            for (int j = 0; j < 8; ++j) rec[j] = nrec[j];
        }
    }
    for (int i = m8; i < n; ++i) {
        unsigned rr = e[i];
        uint2 pp = feat2[((rr & 0xFFFFu) << 6) + lane];
        float vv = __uint_as_float(rr & 0xFFFF0000u);
        s[0] += vv * bf_lo(pp.x);
        s[1] += vv * bf_hi(pp.x);
        s[2] += vv * bf_lo(pp.y);
        s[3] += vv * bf_hi(pp.y);
    }
}

// ---------------------------------------------------------------------------
// Stage 1: input h (packed).  Emits s1, s2-partial (packed uint2), out-partial
// (f32 float4, into d_out).  4 waves per block = 4 rows.
// ---------------------------------------------------------------------------

__global__ __launch_bounds__(256) void stage1_kernel(const uint2* __restrict__ hp2,
                                                     const int* __restrict__ row_ptr,
                                                     const unsigned* __restrict__ csr,
                                                     const float* __restrict__ wseq0,
                                                     const float* __restrict__ wres0,
                                                     const float* __restrict__ wres1,
                                                     uint2* __restrict__ s1p2,
                                                     uint2* __restrict__ s2p2,
                                                     float4* __restrict__ outp4) {
    int t = threadIdx.x, wid = t >> 6, lane = t & 63;
    int r = blockIdx.x * 4 + wid;
    float acc[N_ADJ][4];
    #pragma unroll
    for (int a = 0; a < N_ADJ; ++a) {
        acc[a][0] = acc[a][1] = acc[a][2] = acc[a][3] = 0.f;
        const int* rp = row_ptr + (size_t)a * RPA;
        int beg = __builtin_amdgcn_readfirstlane(rp[r]);
        int end = __builtin_amdgcn_readfirstlane(rp[r + 1]);
        gather_seg(csr + (size_t)a * N_EDGES, beg, end, hp2, lane, acc[a]);
    }
    const float third = 1.f / 3.f;
    float w0 = wseq0[0] * third, w1 = wseq0[1] * third, w2 = wseq0[2] * third;
    float q0 = wres0[0] * 0.25f, q1 = wres0[1] * 0.25f, q2 = wres0[2] * 0.25f, q3 = wres0[3] * 0.25f;
    float u0 = wres1[0] * third, u1 = wres1[1] * third, u2 = wres1[2] * third;
    float s1v[4], s2v[4], ov[4];
    #pragma unroll
    for (int j = 0; j < 4; ++j) {
        s1v[j] = w0 * acc[0][j] + w1 * acc[1][j] + w2 * acc[2][j];
        s2v[j] = q0 * acc[0][j] + q1 * acc[1][j] + q2 * acc[2][j] + q3 * acc[3][j];
        ov[j]  = u0 * acc[0][j] + u1 * acc[1][j] + u2 * acc[3][j];
    }
    int o = r * 64 + lane;
    s1p2[o]  = make_uint2(pack_bf2(s1v[0], s1v[1]), pack_bf2(s1v[2], s1v[3]));
    s2p2[o]  = make_uint2(pack_bf2(s2v[0], s2v[1]), pack_bf2(s2v[2], s2v[3]));
    outp4[o] = make_float4(ov[0], ov[1], ov[2], ov[3]);
}

// ---------------------------------------------------------------------------
// Stage 2: input s1 (packed).  s2 += seq-combo; out-partial += res-combo.
// ---------------------------------------------------------------------------

__global__ __launch_bounds__(256) void stage2_kernel(const uint2* __restrict__ s1p2,
                                                     const int* __restrict__ row_ptr,
                                                     const unsigned* __restrict__ csr,
                                                     const float* __restrict__ wseq0,
                                                     const float* __restrict__ wres1,
                                                     uint2* __restrict__ s2p2,
                                                     float4* __restrict__ outp4) {
    int t = threadIdx.x, wid = t >> 6, lane = t & 63;
    int r = blockIdx.x * 4 + wid;
    float acc[N_ADJ][4];
    #pragma unroll
    for (int a = 0; a < N_ADJ; ++a) {
        acc[a][0] = acc[a][1] = acc[a][2] = acc[a][3] = 0.f;
        const int* rp = row_ptr + (size_t)a * RPA;
        int beg = __builtin_amdgcn_readfirstlane(rp[r]);
        int end = __builtin_amdgcn_readfirstlane(rp[r + 1]);
        gather_seg(csr + (size_t)a * N_EDGES, beg, end, s1p2, lane, acc[a]);
    }
    const float third = 1.f / 3.f;
    float w3 = wseq0[3] * third, w4 = wseq0[4] * third, w5 = wseq0[5] * third;
    float u3 = wres1[3] * third, u4 = wres1[4] * third, u5 = wres1[5] * third;
    int o = r * 64 + lane;
    uint2 sp = s2p2[o];
    float c0 = bf_lo(sp.x) + w3 * acc[0][0] + w4 * acc[1][0] + w5 * acc[2][0];
    float c1 = bf_hi(sp.x) + w3 * acc[0][1] + w4 * acc[1][1] + w5 * acc[2][1];
    float c2 = bf_lo(sp.y) + w3 * acc[0][2] + w4 * acc[1][2] + w5 * acc[2][2];
    float c3 = bf_hi(sp.y) + w3 * acc[0][3] + w4 * acc[1][3] + w5 * acc[2][3];
    s2p2[o] = make_uint2(pack_bf2(c0, c1), pack_bf2(c2, c3));
    float4 op = outp4[o];
    op.x += u3 * acc[0][0] + u4 * acc[1][0] + u5 * acc[3][0];
    op.y += u3 * acc[0][1] + u4 * acc[1][1] + u5 * acc[3][1];
    op.z += u3 * acc[0][2] + u4 * acc[1][2] + u5 * acc[3][2];
    op.w += u3 * acc[0][3] + u4 * acc[1][3] + u5 * acc[3][3];
    outp4[o] = op;
}

// ---------------------------------------------------------------------------
// Stage 3: input s2 (adjacencies 0,1), add out-partial, LayerNorm (pure wave
// shuffle reduction -- no LDS, no syncthreads), exact GELU.
// ---------------------------------------------------------------------------

__global__ __launch_bounds__(256) void stage3_kernel(const uint2* __restrict__ s2p2,
                                                     const int* __restrict__ row_ptr,
                                                     const unsigned* __restrict__ csr,
                                                     const float* __restrict__ wseq1,
                                                     float4* __restrict__ outp4) {
    int t = threadIdx.x, wid = t >> 6, lane = t & 63;
    int r = blockIdx.x * 4 + wid;
    float acc[2][4];
    #pragma unroll
    for (int a = 0; a < 2; ++a) {
        acc[a][0] = acc[a][1] = acc[a][2] = acc[a][3] = 0.f;
        const int* rp = row_ptr + (size_t)a * RPA;
        int beg = __builtin_amdgcn_readfirstlane(rp[r]);
        int end = __builtin_amdgcn_readfirstlane(rp[r + 1]);
        gather_seg(csr + (size_t)a * N_EDGES, beg, end, s2p2, lane, acc[a]);
    }
    float e0 = wseq1[0] * 0.5f, e1 = wseq1[1] * 0.5f;
    int o = r * 64 + lane;
    float4 op = outp4[o];
    float v0 = op.x + e0 * acc[0][0] + e1 * acc[1][0];
    float v1 = op.y + e0 * acc[0][1] + e1 * acc[1][1];
    float v2 = op.z + e0 * acc[0][2] + e1 * acc[1][2];
    float v3 = op.w + e0 * acc[0][3] + e1 * acc[1][3];

    float sv = v0 + v1 + v2 + v3;
    float sq = v0 * v0 + v1 * v1 + v2 * v2 + v3 * v3;
    #pragma unroll
    for (int off = 32; off > 0; off >>= 1) {
        sv += __shfl_xor(sv, off, 64);
        sq += __shfl_xor(sq, off, 64);
    }
    float mu   = sv * (1.f / 256.f);
    float var  = sq * (1.f / 256.f) - mu * mu;
    float rstd = rsqrtf(var + 1e-5f);
    float y0 = (v0 - mu) * rstd;
    float y1 = (v1 - mu) * rstd;
    float y2 = (v2 - mu) * rstd;
    float y3 = (v3 - mu) * rstd;
    const float is2 = 0.70710678118654752440f;
    outp4[o] = make_float4(0.5f * y0 * (1.f + erff(y0 * is2)),
                           0.5f * y1 * (1.f + erff(y1 * is2)),
                           0.5f * y2 * (1.f + erff(y2 * is2)),
                           0.5f * y3 * (1.f + erff(y3 * is2)));
}

// ---------------------------------------------------------------------------

extern "C" void kernel_launch(void* const* d_in, const int* in_sizes, int n_in,
                              void* d_out, int out_size, void* d_ws, size_t ws_size,
                              hipStream_t stream) {
    const float* x     = (const float*)d_in[0];
    const int*   rows  = (const int*)d_in[1];
    const int*   cols  = (const int*)d_in[2];
    const float* vals  = (const float*)d_in[3];
    const float* W     = (const float*)d_in[4];
    const float* b     = (const float*)d_in[5];
    const float* wseq0 = (const float*)d_in[6];  // (2,3)
    const float* wseq1 = (const float*)d_in[7];  // (2,)
    const float* wres0 = (const float*)d_in[8];  // (1,4)
    const float* wres1 = (const float*)d_in[9];  // (2,3)
    float4* outp4 = (float4*)d_out;

    char* p = (char*)d_ws;
    unsigned* hp  = (unsigned*)p; p += (size_t)N_NODES * DH * 4;      // 10.24 MB
    unsigned* s1p = (unsigned*)p; p += (size_t)N_NODES * DH * 4;      // 10.24 MB
    unsigned* s2p = (unsigned*)p; p += (size_t)N_NODES * DH * 4;      // 10.24 MB
    int* row_ptr  = (int*)p;      p += (size_t)N_ADJ * RPA * 4;       // 320 KB
    int* cnt      = (int*)p;      p += (size_t)N_ADJ * N_NODES * 4;   // 320 KB
    int* work     = (int*)p;      p += (size_t)N_ADJ * N_NODES * 4;   // 320 KB
    uint4* wh     = (uint4*)p;    p += 8192 * 16;                     // 128 KB
    uint4* wl     = (uint4*)p;    p += 8192 * 16;                     // 128 KB
    unsigned* csr = (unsigned*)p;                                     // 5.12 MB

    hipMemsetAsync(cnt, 0, (size_t)N_ADJ * N_NODES * sizeof(int), stream);

    dim3 egrid((N_EDGES + 255) / 256, N_ADJ);
    hist_kernel<<<egrid, 256, 0, stream>>>(rows, cnt);
    scan_kernel<<<N_ADJ, 1024, 0, stream>>>((const int4*)cnt, row_ptr, work);
    scatter_kernel<<<egrid, 256, 0, stream>>>(rows, cols, vals, work, csr);

    wfrag_kernel<<<32, 256, 0, stream>>>(W, wh, wl);
    mfma_matmul_kernel<<<313, 256, 0, stream>>>(x, wh, wl, b, hp);

    stage1_kernel<<<N_NODES / 4, 256, 0, stream>>>((const uint2*)hp, row_ptr, csr,
                                                   wseq0, wres0, wres1,
                                                   (uint2*)s1p, (uint2*)s2p, outp4);
    stage2_kernel<<<N_NODES / 4, 256, 0, stream>>>((const uint2*)s1p, row_ptr, csr,
                                                   wseq0, wres1, (uint2*)s2p, outp4);
    stage3_kernel<<<N_NODES / 4, 256, 0, stream>>>((const uint2*)s2p, row_ptr, csr,
                                                   wseq1, outp4);
}